// Round 11
// baseline (568.762 us; speedup 1.0000x reference)
//
#include <hip/hip_runtime.h>
#include <hip/hip_bf16.h>
#include <math.h>

#define NB 4
#define LL 16384
#define CC 256
#define NHD 8
#define DH 32
#define MROWS (NB*LL)   // 65536

typedef __hip_bfloat16 bf16;
typedef __attribute__((ext_vector_type(8))) short short8;
typedef __attribute__((ext_vector_type(4))) float floatx4;

__device__ __forceinline__ float u2f(unsigned short u) {
  return __uint_as_float(((unsigned)u) << 16);
}
__device__ __forceinline__ unsigned short f2u(float f) {
  bf16 t = __float2bfloat16(f);
  unsigned short u;
  __builtin_memcpy(&u, &t, 2);
  return u;
}

// ---------------- f32 -> bf16 bulk convert (8 elems/thread) --------------
__global__ __launch_bounds__(256) void convert_kernel(
    const float* __restrict__ in, bf16* __restrict__ out, int n8)
{
  int i = blockIdx.x*256 + threadIdx.x;
  if (i >= n8) return;
  const float4* p = (const float4*)in + (size_t)i*2;
  float4 f0 = p[0], f1 = p[1];
  unsigned short t[8] = {f2u(f0.x),f2u(f0.y),f2u(f0.z),f2u(f0.w),
                         f2u(f1.x),f2u(f1.y),f2u(f1.z),f2u(f1.w)};
  *(uint4*)(out + (size_t)i*8) = *(uint4*)t;
}

// ---------------- all weights f32 -> bf16, one dispatch ------------------
__global__ __launch_bounds__(256) void convert_weights_kernel(
    const float* __restrict__ Wq, const float* __restrict__ Wk,
    const float* __restrict__ Wv, const float* __restrict__ Wm,
    const float* __restrict__ W1, const float* __restrict__ W2,
    bf16* __restrict__ dst)
{
  int i = blockIdx.x*256 + threadIdx.x;    // 8-elem unit; total 81920 units
  const float* src; int off8;
  if      (i < 8192)  { src = Wq; off8 = i; }
  else if (i < 16384) { src = Wk; off8 = i-8192; }
  else if (i < 24576) { src = Wv; off8 = i-16384; }
  else if (i < 32768) { src = Wm; off8 = i-24576; }
  else if (i < 65536) { src = W1; off8 = i-32768; }
  else                { src = W2; off8 = i-65536; }
  const float4* p = (const float4*)src + (size_t)off8*2;
  float4 f0 = p[0], f1 = p[1];
  unsigned short t[8] = {f2u(f0.x),f2u(f0.y),f2u(f0.z),f2u(f0.w),
                         f2u(f1.x),f2u(f1.y),f2u(f1.z),f2u(f1.w)};
  *(uint4*)(dst + (size_t)i*8) = *(uint4*)t;
}

// ---------------- 4-wave 128x256 MFMA GEMM (full-row blocks) -------------
// C[M,N] = epi( A[M,K] @ B[N,K]^T ), all bf16.  BK=32.
// Proven r9/r10 skeleton (global_load_lds staging, one barrier pair per
// K-step, r8-verified XOR swizzle) widened to 256 output cols per block:
// waves 2x2 cover 64 rows x 128 cols each (acc[4][8], 32 MFMA/step/wave),
// doubling MFMA per byte of LDS staging. Full rows per block enable
// in-epilogue LayerNorm (EPI 4/5).
// sc = 256-col super-block (N=512 only); paired on same XCD for A reuse.
// EPI: 0 none, 1 relu, 2 elu+1+RoPE,
//      3 fused k|v: sc=0 -> rope to C, sc=1 -> plain to C2 (both stride 256)
//      4 LN1 fused: C = LN(acc; g,b) bf16
//      5 LN2+add fused: fout = xin + LN(acc; g,b)  (f32)
template<int EPI>
__global__ __launch_bounds__(256) void gemm_row(
    const bf16* __restrict__ A0, int K0, const bf16* __restrict__ A1,
    const bf16* __restrict__ B, bf16* __restrict__ C, bf16* __restrict__ C2,
    const float* __restrict__ g, const float* __restrict__ b,
    const float* __restrict__ xin, float* __restrict__ fout,
    int M, int N, int K)
{
  __shared__ __align__(16) unsigned short As[128*32];  // 8 KB
  __shared__ __align__(16) unsigned short Bs[256*32];  // 16 KB
  __shared__ float ssum[128][2], ssq[128][2];          // 2 KB (EPI 4/5)
  const int tid  = threadIdx.x;
  const int lane = tid & 63, wave = tid >> 6;
  const int wm = wave & 1, wn = wave >> 1;
  const int l15 = lane & 15, quad = lane >> 4;

  // XCD map: sc pairs of one bm land on the same XCD (A L2 reuse)
  const int nsc = N >> 8;                       // 1 or 2
  const int xcd = blockIdx.x & 7;
  const int s   = blockIdx.x >> 3;
  const int sc  = (nsc == 2) ? (s & 1) : 0;
  const int seq = (nsc == 2) ? (s >> 1) : s;
  const int bm  = seq*8 + xcd;                  // 0..M/128-1

  const int swz = quad ^ ((l15 >> 1) & 3);      // fragment read slot (r8)

  floatx4 acc[4][8] = {};

  for (int kt = 0; kt < K; kt += 32) {
    const bf16* aSrc; int lda, kof;
    if (kt < K0) { aSrc = A0; lda = K0;     kof = kt; }
    else         { aSrc = A1; lda = K - K0; kof = kt - K0; }
    // A tile 128x32: 512 units, 2/thread; XOR-swizzled source, linear dest
    #pragma unroll
    for (int m = 0; m < 2; m++) {
      int U = m*256 + tid;
      int row = U >> 2, q = U & 3;
      int gq = q ^ ((row >> 1) & 3);
      const bf16* gp = aSrc + (size_t)(bm*128 + row)*lda + kof + gq*8;
      __builtin_amdgcn_global_load_lds(
          (const __attribute__((address_space(1))) void*)gp,
          (__attribute__((address_space(3))) void*)(As + (size_t)U*8),
          16, 0, 0);
    }
    // B tile 256x32: 1024 units, 4/thread
    #pragma unroll
    for (int m = 0; m < 4; m++) {
      int U = m*256 + tid;
      int row = U >> 2, q = U & 3;
      int gq = q ^ ((row >> 1) & 3);
      const bf16* gp = B + (size_t)(sc*256 + row)*K + kt + gq*8;
      __builtin_amdgcn_global_load_lds(
          (const __attribute__((address_space(1))) void*)gp,
          (__attribute__((address_space(3))) void*)(Bs + (size_t)U*8),
          16, 0, 0);
    }
    __syncthreads();
    short8 a[4], bb[8];
    #pragma unroll
    for (int i = 0; i < 4; i++)
      a[i] = *(const short8*)&As[((wm*64 + i*16 + l15)*4 + swz)*8];
    #pragma unroll
    for (int j = 0; j < 8; j++)
      bb[j] = *(const short8*)&Bs[((wn*128 + j*16 + l15)*4 + swz)*8];
    #pragma unroll
    for (int i = 0; i < 4; i++)
      #pragma unroll
      for (int j = 0; j < 8; j++)
        acc[i][j] = __builtin_amdgcn_mfma_f32_16x16x32_bf16(a[i], bb[j], acc[i][j], 0, 0, 0);
    __syncthreads();
  }

  // C/D layout: col = lane&15 (+j*16), row = quad*4 + reg (+i*16)
  const int colc = wn*128 + l15;                // local col base
  const int lr0  = wm*64 + quad*4;              // local row base (+i*16+r)

  if (EPI == 2 || EPI == 3) {
    if (EPI == 2 || sc == 0) {
      // RoPE (pair-channel constants depend only on l15 and j&1)
      const int pp_e = l15 >> 1;
      const int pp_o = pp_e + 8;
      const int par  = pp_e & 1;
      const float dv_e = __expf(-1.15129254650564f * (float)(pp_e >> 1));
      const float dv_o = __expf(-1.15129254650564f * (float)(pp_o >> 1));
      const float sgn = (l15 & 1) ? 1.f : -1.f;
      #pragma unroll
      for (int i = 0; i < 4; i++) {
        #pragma unroll
        for (int r = 0; r < 4; r++) {
          int row = bm*128 + lr0 + i*16 + r;
          int l = row & (LL-1);
          float pos = par ? (float)((l & 127) + 1) : (float)((l >> 7) + 1);
          float ae = pos * dv_e, ao = pos * dv_o;
          float se = __sinf(ae), ce = __cosf(ae);
          float so = __sinf(ao), co = __cosf(ao);
          #pragma unroll
          for (int j = 0; j < 8; j++) {
            float sv = (j & 1) ? so : se;
            float cv = (j & 1) ? co : ce;
            float v = acc[i][j][r];
            v = v > 0.f ? v + 1.f : __expf(v);   // elu+1
            float p = __shfl_xor(v, 1, 64);      // pair partner channel
            float o = fmaf(v, cv, sgn * p * sv);
            C[(size_t)row*256 + colc + j*16] = __float2bfloat16(o);
          }
        }
      }
    } else {
      // v half: plain store to C2, stride 256
      #pragma unroll
      for (int i = 0; i < 4; i++)
        #pragma unroll
        for (int j = 0; j < 8; j++)
          #pragma unroll
          for (int r = 0; r < 4; r++)
            C2[(size_t)(bm*128 + lr0 + i*16 + r)*256 + colc + j*16] =
                __float2bfloat16(acc[i][j][r]);
    }
  } else if (EPI == 4 || EPI == 5) {
    // fused LayerNorm over the full 256-col row
    #pragma unroll
    for (int i = 0; i < 4; i++) {
      #pragma unroll
      for (int r = 0; r < 4; r++) {
        float sv = 0.f, qv = 0.f;
        #pragma unroll
        for (int j = 0; j < 8; j++) { float v = acc[i][j][r]; sv += v; qv += v*v; }
        #pragma unroll
        for (int o = 1; o < 16; o <<= 1) {
          sv += __shfl_xor(sv, o, 64);
          qv += __shfl_xor(qv, o, 64);
        }
        if (l15 == 0) {
          int lr = lr0 + i*16 + r;
          ssum[lr][wn] = sv; ssq[lr][wn] = qv;
        }
      }
    }
    __syncthreads();
    float gv[8], bv[8];
    #pragma unroll
    for (int j = 0; j < 8; j++) { gv[j] = g[colc + j*16]; bv[j] = b[colc + j*16]; }
    #pragma unroll
    for (int i = 0; i < 4; i++) {
      #pragma unroll
      for (int r = 0; r < 4; r++) {
        int lr = lr0 + i*16 + r;
        size_t row = (size_t)(bm*128) + lr;
        float S = ssum[lr][0] + ssum[lr][1];
        float Q = ssq[lr][0] + ssq[lr][1];
        float mean = S * (1.f/256.f);
        float rstd = rsqrtf(Q*(1.f/256.f) - mean*mean + 1e-5f);
        #pragma unroll
        for (int j = 0; j < 8; j++) {
          float lnv = (acc[i][j][r] - mean)*rstd*gv[j] + bv[j];
          if (EPI == 4)
            C[row*256 + colc + j*16] = __float2bfloat16(lnv);
          else
            fout[row*256 + colc + j*16] = xin[row*256 + colc + j*16] + lnv;
        }
      }
    }
  } else {
    #pragma unroll
    for (int i = 0; i < 4; i++)
      #pragma unroll
      for (int j = 0; j < 8; j++)
        #pragma unroll
        for (int r = 0; r < 4; r++) {
          float v = acc[i][j][r];
          if (EPI == 1) v = fmaxf(v, 0.f);
          C[(size_t)(bm*128 + lr0 + i*16 + r)*N + sc*256 + colc + j*16] =
              __float2bfloat16(v);
        }
  }
}

// ---------------- KV partials: no atomics --------------------------------
#define KVPAD 36   // f32 row stride: 144 B = 16B-aligned, breaks bank cycle
__global__ __launch_bounds__(256) void kv_kernel(
    const bf16* __restrict__ Kr, const bf16* __restrict__ V,
    float* __restrict__ KVp, float* __restrict__ Ksp)
{
  __shared__ __align__(16) float Kf[128*KVPAD];  // 18 KB
  __shared__ __align__(16) float Vf[128*KVPAD];  // 18 KB
  const int nh = blockIdx.x;               // n*8+h
  const int n = nh >> 3, h = nh & 7;
  const int cs = blockIdx.y;               // 32 chunks of 512 rows
  const int s0 = cs << 9;
  const int tid = threadIdx.x;
  const int d = tid >> 3, e0 = (tid & 7) << 2;

  float acc0 = 0.f, acc1 = 0.f, acc2 = 0.f, acc3 = 0.f, ks = 0.f;

  for (int sub = 0; sub < 4; sub++) {
    const int sb = s0 + sub*128;
    #pragma unroll
    for (int u = tid; u < 512; u += 256) {
      int row = u >> 2, d0 = (u & 3) << 3;
      size_t gg = (((size_t)(n*LL + sb + row)*NHD + h) << 5) + d0;
      short8 k8 = *(const short8*)(Kr + gg);
      short8 v8 = *(const short8*)(V + gg);
      float* kp = &Kf[row*KVPAD + d0];
      float* vp = &Vf[row*KVPAD + d0];
      float4 ka = {u2f((unsigned short)k8[0]), u2f((unsigned short)k8[1]),
                   u2f((unsigned short)k8[2]), u2f((unsigned short)k8[3])};
      float4 kb = {u2f((unsigned short)k8[4]), u2f((unsigned short)k8[5]),
                   u2f((unsigned short)k8[6]), u2f((unsigned short)k8[7])};
      float4 va = {u2f((unsigned short)v8[0]), u2f((unsigned short)v8[1]),
                   u2f((unsigned short)v8[2]), u2f((unsigned short)v8[3])};
      float4 vb = {u2f((unsigned short)v8[4]), u2f((unsigned short)v8[5]),
                   u2f((unsigned short)v8[6]), u2f((unsigned short)v8[7])};
      *(float4*)kp = ka; *(float4*)(kp+4) = kb;
      *(float4*)vp = va; *(float4*)(vp+4) = vb;
    }
    __syncthreads();
    #pragma unroll 8
    for (int ss = 0; ss < 128; ss++) {
      float kd = Kf[ss*KVPAD + d];                     // broadcast (8 lanes)
      float4 v4 = *(const float4*)&Vf[ss*KVPAD + e0];  // broadcast (8 lanes)
      acc0 = fmaf(kd, v4.x, acc0);
      acc1 = fmaf(kd, v4.y, acc1);
      acc2 = fmaf(kd, v4.z, acc2);
      acc3 = fmaf(kd, v4.w, acc3);
      ks += kd;
    }
    __syncthreads();
  }

  float* kvp = KVp + (((size_t)nh << 5) + cs) * 1024 + (tid << 2);
  kvp[0] = acc0; kvp[1] = acc1; kvp[2] = acc2; kvp[3] = acc3;
  if ((tid & 7) == 0) Ksp[(((size_t)nh << 5) + cs) * 32 + d] = ks;
}

// ---------------- reduce partials -> KV[nh][1024], Ksum[nh][32] ----------
__global__ __launch_bounds__(256) void reduce_kv_kernel(
    const float* __restrict__ KVp, const float* __restrict__ Ksp,
    float* __restrict__ KV, float* __restrict__ Ksum)
{
  const int nh = blockIdx.x;
  const int tid = threadIdx.x;
  float4 acc = {0.f,0.f,0.f,0.f};
  #pragma unroll 8
  for (int cs = 0; cs < 32; cs++) {
    float4 p = *(const float4*)(KVp + (((size_t)nh << 5) + cs) * 1024 + (tid << 2));
    acc.x += p.x; acc.y += p.y; acc.z += p.z; acc.w += p.w;
  }
  *(float4*)(KV + ((size_t)nh << 10) + (tid << 2)) = acc;
  if (tid < 32) {
    float s = 0.f;
    #pragma unroll 8
    for (int cs = 0; cs < 32; cs++)
      s += Ksp[(((size_t)nh << 5) + cs) * 32 + tid];
    Ksum[(nh << 5) + tid] = s;
  }
}

// ---------------- out[l,h,e] = (Q_h . KV_h[:,e]) / (Q_h . Ksum_h + eps) ---
__global__ __launch_bounds__(256) void attn_out_kernel(
    const bf16* __restrict__ Qr, const float* __restrict__ KV,
    const float* __restrict__ Ksum, bf16* __restrict__ Out)
{
  __shared__ float KVs[8192];
  __shared__ float Kss[256];
  __shared__ float Qs[16][256];
  const int blk = blockIdx.x;            // 4096 blocks, 16 rows each
  const int n = blk >> 10;               // 1024 blocks per batch
  const int tid = threadIdx.x;
  const size_t rowBase = (size_t)blk * 16;
  for (int i = tid; i < 8192; i += 256) KVs[i] = KV[((size_t)n << 13) + i];
  Kss[tid] = Ksum[(n << 8) + tid];
  #pragma unroll
  for (int it = 0; it < 2; it++) {
    int i = it*256 + tid;                // 8-elem unit, 512 units total
    short8 u = *(const short8*)(Qr + (rowBase << 8) + (size_t)i*8);
    float* qp = ((float*)Qs) + (size_t)i*8;
    #pragma unroll
    for (int j = 0; j < 8; j++) qp[j] = u2f((unsigned short)u[j]);
  }
  __syncthreads();
  const int h = tid >> 5, e = tid & 31;
  const float* kvh = &KVs[(h << 10) + e];
  const float* ksh = &Kss[h << 5];
  for (int r = 0; r < 16; r++) {
    const float* qh = &Qs[r][h << 5];
    float denom = 1e-6f;
    float num = 0.f;
    #pragma unroll
    for (int d = 0; d < 32; d++) {
      float qd = qh[d];
      denom = fmaf(qd, ksh[d], denom);
      num   = fmaf(qd, kvh[d << 5], num);
    }
    Out[((rowBase + r) << 8) + tid] = __float2bfloat16(num / denom);
  }
}

extern "C" void kernel_launch(void* const* d_in, const int* in_sizes, int n_in,
                              void* d_out, int out_size, void* d_ws, size_t ws_size,
                              hipStream_t stream) {
  const float* x   = (const float*)d_in[0];
  const float* src = (const float*)d_in[1];
  const float* Wq  = (const float*)d_in[2];
  const float* Wk  = (const float*)d_in[3];
  const float* Wv  = (const float*)d_in[4];
  const float* Wm  = (const float*)d_in[5];
  const float* W1  = (const float*)d_in[6];
  const float* W2  = (const float*)d_in[7];
  const float* g1  = (const float*)d_in[8];
  const float* b1  = (const float*)d_in[9];
  const float* g2  = (const float*)d_in[10];
  const float* b2  = (const float*)d_in[11];
  float* out = (float*)d_out;

  bf16* ws = (bf16*)d_ws;
  const size_t BUFH = (size_t)MROWS * CC;   // 16,777,216 bf16 = 32 MB
  bf16* R0 = ws;               // xb (live until W1 gemm)
  bf16* R1 = ws + BUFH;        // sb -> q -> h1(lo)
  bf16* R2 = ws + 2*BUFH;      // k -> attn -> h1(hi)
  bf16* R3 = ws + 3*BUFH;      // v -> msg
  bf16* WB = ws + 4*BUFH;      // bf16 weights, 655360 elems (1.25 MB)
  bf16* wq = WB, *wk = WB+65536, *wv = WB+131072, *wm = WB+196608,
      *w1 = WB+262144, *w2 = WB+524288;
  float* KV   = (float*)(WB + 655360);      // 32768 f32
  float* Ksum = KV + NB*NHD*DH*DH;          // 1024 f32
  // KV partials live in d_out (64 MB, fully overwritten by fused W2 gemm):
  float* KVp = out;                         // 32*32*1024 f32 = 4 MB
  float* Ksp = out + 32*32*1024;            // 32*32*32 f32 = 128 KB

  dim3 blk(256);
  const int n8 = MROWS*CC/8;
  convert_kernel<<<(n8+255)/256, blk, 0, stream>>>(x,   R0, n8);
  convert_kernel<<<(n8+255)/256, blk, 0, stream>>>(src, R1, n8);
  convert_weights_kernel<<<320, blk, 0, stream>>>(Wq, Wk, Wv, Wm, W1, W2, WB);

  const int GR1 = MROWS/128;        // 512 blocks (N=256)
  const int GR2 = (MROWS/128)*2;    // 1024 blocks (N=512)
  // fused: [k|v] = sb @ [wk;wv]^T -> k(rope)->R2, v->R3 (wk,wv contiguous)
  gemm_row<3><<<GR2, blk, 0, stream>>>(R1, CC, nullptr, wk, R2, R3,
                                       nullptr, nullptr, nullptr, nullptr,
                                       MROWS, 2*CC, CC);
  // KV + Ksum via partials (no atomics)
  kv_kernel<<<dim3(NB*NHD, 32), blk, 0, stream>>>(R2, R3, KVp, Ksp);
  reduce_kv_kernel<<<NB*NHD, blk, 0, stream>>>(KVp, Ksp, KV, Ksum);
  // q = rope(elu(xb@Wq^T)+1) -> R1 (sb dead)
  gemm_row<2><<<GR1, blk, 0, stream>>>(R0, CC, nullptr, wq, R1, nullptr,
                                       nullptr, nullptr, nullptr, nullptr,
                                       MROWS, CC, CC);
  // attn: q(R1) -> R2 (k dead)
  attn_out_kernel<<<MROWS/16, blk, 0, stream>>>(R1, KV, Ksum, R2);
  // msg = LN1(attn @ Wm^T) fused -> R3 (v dead)
  gemm_row<4><<<GR1, blk, 0, stream>>>(R2, CC, nullptr, wm, R3, nullptr,
                                       g1, b1, nullptr, nullptr,
                                       MROWS, CC, CC);
  // h1 = relu([xb(R0) | msg(R3)] @ W1^T) -> R1..R2 (64 MB contiguous)
  gemm_row<1><<<GR2, blk, 0, stream>>>(R0, CC, R3, w1, R1, nullptr,
                                       nullptr, nullptr, nullptr, nullptr,
                                       MROWS, 2*CC, 2*CC);
  // out = x + LN2(h1 @ W2^T) fused, f32 out directly
  gemm_row<5><<<GR1, blk, 0, stream>>>(nullptr, 0, R1, w2, nullptr, nullptr,
                                       g2, b2, x, out,
                                       MROWS, CC, 2*CC);
}

// Round 12
// 468.681 us; speedup vs baseline: 1.2135x; 1.2135x over previous
//
#include <hip/hip_runtime.h>
#include <hip/hip_bf16.h>
#include <math.h>

#define NB 4
#define LL 16384
#define CC 256
#define NHD 8
#define DH 32
#define MROWS (NB*LL)   // 65536

typedef __hip_bfloat16 bf16;
typedef __attribute__((ext_vector_type(8))) short short8;
typedef __attribute__((ext_vector_type(4))) float floatx4;

__device__ __forceinline__ float u2f(unsigned short u) {
  return __uint_as_float(((unsigned)u) << 16);
}
__device__ __forceinline__ unsigned short f2u(float f) {
  bf16 t = __float2bfloat16(f);
  unsigned short u;
  __builtin_memcpy(&u, &t, 2);
  return u;
}

// ---------------- f32 -> bf16 bulk convert (8 elems/thread) --------------
__global__ __launch_bounds__(256) void convert_kernel(
    const float* __restrict__ in, bf16* __restrict__ out, int n8)
{
  int i = blockIdx.x*256 + threadIdx.x;
  if (i >= n8) return;
  const float4* p = (const float4*)in + (size_t)i*2;
  float4 f0 = p[0], f1 = p[1];
  unsigned short t[8] = {f2u(f0.x),f2u(f0.y),f2u(f0.z),f2u(f0.w),
                         f2u(f1.x),f2u(f1.y),f2u(f1.z),f2u(f1.w)};
  *(uint4*)(out + (size_t)i*8) = *(uint4*)t;
}

// ---------------- all weights f32 -> bf16, one dispatch ------------------
__global__ __launch_bounds__(256) void convert_weights_kernel(
    const float* __restrict__ Wq, const float* __restrict__ Wk,
    const float* __restrict__ Wv, const float* __restrict__ Wm,
    const float* __restrict__ W1, const float* __restrict__ W2,
    bf16* __restrict__ dst)
{
  int i = blockIdx.x*256 + threadIdx.x;    // 8-elem unit; total 81920 units
  const float* src; int off8;
  if      (i < 8192)  { src = Wq; off8 = i; }
  else if (i < 16384) { src = Wk; off8 = i-8192; }
  else if (i < 24576) { src = Wv; off8 = i-16384; }
  else if (i < 32768) { src = Wm; off8 = i-24576; }
  else if (i < 65536) { src = W1; off8 = i-32768; }
  else                { src = W2; off8 = i-65536; }
  const float4* p = (const float4*)src + (size_t)off8*2;
  float4 f0 = p[0], f1 = p[1];
  unsigned short t[8] = {f2u(f0.x),f2u(f0.y),f2u(f0.z),f2u(f0.w),
                         f2u(f1.x),f2u(f1.y),f2u(f1.z),f2u(f1.w)};
  *(uint4*)(dst + (size_t)i*8) = *(uint4*)t;
}

// ---------------- m97-style 4-wave 128x128 MFMA GEMM ---------------------
// C[M,N] = epi( A[M,K] @ B[N,K]^T ), all bf16.  BK=32.
// r10 proven base (483.6us: global_load_lds staging, r8 XOR swizzle, 0
// bank conflicts) + T3/T4 pipelining: DOUBLE-BUFFERED LDS with counted
// s_waitcnt vmcnt(4) and RAW s_barrier (no vmcnt drain, unlike
// __syncthreads). Per K-step each wave: issue 4 staging loads for tile
// t+1 (other buffer), wait vmcnt(4) = own tile-t loads landed, raw
// barrier (=> all waves' tile-t loads landed), ds_read+MFMA, raw barrier
// (closes WAR: t+2 staging lands after all waves finished reading).
// Tile t+1's loads stay in flight across the barrier - the drain that
// cost ~1 HBM latency per K-step is gone.
// EPI: 0 none, 1 relu, 2 elu+1+RoPE (N=256),
//      3 fused k|v: bn<2 -> rope to C (stride 256), bn>=2 -> plain to C2.
template<int EPI>
__global__ __launch_bounds__(256) void gemm_m97(
    const bf16* __restrict__ A0, int K0, const bf16* __restrict__ A1,
    const bf16* __restrict__ B, bf16* __restrict__ C, bf16* __restrict__ C2,
    int M, int N, int K)
{
  __shared__ __align__(16) unsigned short SM[16384];  // 32 KB
  // Abuf(b) = SM + b*4096 ; Bbuf(b) = SM + 8192 + b*4096  (ushorts)
  const int tid  = threadIdx.x;
  const int lane = tid & 63, wave = tid >> 6;
  const int wm = wave & 1, wn = wave >> 1;
  const int l15 = lane & 15, quad = lane >> 4;

  // swizzle: blocks with same bm, all bn sit 8 apart -> same XCD L2 shares A
  const int nbn = N >> 7;                       // 2 or 4
  const int sh  = (nbn == 2) ? 4 : 5;           // log2(8*nbn)
  const int w   = blockIdx.x & ((1 << sh) - 1);
  const int g   = blockIdx.x >> sh;
  const int bm  = g*8 + (w & 7);
  const int bn  = w >> 3;

  const int srow  = tid >> 2;                   // 0..63 (row within chunk)
  const int gq    = (tid & 3) ^ ((tid >> 3) & 3);  // swizzled source unit
  const int skcol = gq << 3;                    // source k-offset (elements)
  const int swz   = quad ^ ((l15 >> 1) & 3);    // fragment read slot

  floatx4 acc[4][4] = {};
  const int NT = K >> 5;

  // stage tile t into buffer buf: 2 A loads + 2 B loads per thread
  #define STAGE(t, buf)                                                     \
  {                                                                         \
    int kt_ = (t) << 5;                                                     \
    const bf16* aS_; int lda_, kof_;                                        \
    if (kt_ < K0) { aS_ = A0; lda_ = K0;     kof_ = kt_; }                  \
    else          { aS_ = A1; lda_ = K - K0; kof_ = kt_ - K0; }             \
    _Pragma("unroll")                                                       \
    for (int c = 0; c < 2; c++) {                                           \
      const bf16* gp_ = aS_ + (size_t)(bm*128 + c*64 + srow)*lda_ + kof_ + skcol; \
      __builtin_amdgcn_global_load_lds(                                     \
          (const __attribute__((address_space(1))) void*)gp_,               \
          (__attribute__((address_space(3))) void*)(SM + (buf)*4096 + c*2048 + tid*8), \
          16, 0, 0);                                                        \
    }                                                                       \
    _Pragma("unroll")                                                       \
    for (int c = 0; c < 2; c++) {                                           \
      const bf16* gp_ = B + (size_t)(bn*128 + c*64 + srow)*K + kt_ + skcol; \
      __builtin_amdgcn_global_load_lds(                                     \
          (const __attribute__((address_space(1))) void*)gp_,               \
          (__attribute__((address_space(3))) void*)(SM + 8192 + (buf)*4096 + c*2048 + tid*8), \
          16, 0, 0);                                                        \
    }                                                                       \
  }

  STAGE(0, 0);
  for (int t = 0; t < NT; ++t) {
    const int cur = t & 1;
    if (t + 1 < NT) {
      STAGE(t + 1, cur ^ 1);
      asm volatile("s_waitcnt vmcnt(4)" ::: "memory");  // own tile-t loads in
    } else {
      asm volatile("s_waitcnt vmcnt(0)" ::: "memory");
    }
    __builtin_amdgcn_sched_barrier(0);
    __builtin_amdgcn_s_barrier();          // all waves' tile-t loads landed
    __builtin_amdgcn_sched_barrier(0);
    short8 a[4], b[4];
    #pragma unroll
    for (int i = 0; i < 4; i++) {
      a[i] = *(const short8*)&SM[(size_t)cur*4096 + ((wm*64 + i*16 + l15)*4 + swz)*8];
      b[i] = *(const short8*)&SM[8192 + (size_t)cur*4096 + ((wn*64 + i*16 + l15)*4 + swz)*8];
    }
    #pragma unroll
    for (int i = 0; i < 4; i++)
      #pragma unroll
      for (int j = 0; j < 4; j++)
        acc[i][j] = __builtin_amdgcn_mfma_f32_16x16x32_bf16(a[i], b[j], acc[i][j], 0, 0, 0);
    __builtin_amdgcn_sched_barrier(0);
    __builtin_amdgcn_s_barrier();          // WAR: reads done before t+2 lands
  }
  #undef STAGE

  // epilogue: C/D layout col=lane&15, row=quad*4+reg
  const int row0 = bm*128 + wm*64 + quad*4;
  const int col0 = bn*128 + wn*64 + l15;
  const bool doRope = (EPI == 2) || (EPI == 3 && bn < 2);
  if (doRope) {
    // pair-channel constants, fixed per lane (col0&31 == l15)
    const int pp_e = l15 >> 1;        // j even
    const int pp_o = pp_e + 8;        // j odd
    const int par  = pp_e & 1;        // i-angle (0) vs j-angle (1)
    const float dv_e = __expf(-1.15129254650564f * (float)(pp_e >> 1));
    const float dv_o = __expf(-1.15129254650564f * (float)(pp_o >> 1));
    const float sgn = (l15 & 1) ? 1.f : -1.f;
    #pragma unroll
    for (int i = 0; i < 4; i++) {
      #pragma unroll
      for (int r = 0; r < 4; r++) {
        int row = row0 + i*16 + r;
        int l = row & (LL-1);
        float pos = par ? (float)((l & 127) + 1) : (float)((l >> 7) + 1);
        float ae = pos * dv_e, ao = pos * dv_o;
        float se = __sinf(ae), ce = __cosf(ae);
        float so = __sinf(ao), co = __cosf(ao);
        #pragma unroll
        for (int j = 0; j < 4; j++) {
          float s = (j & 1) ? so : se;
          float c = (j & 1) ? co : ce;
          float v = acc[i][j][r];
          v = v > 0.f ? v + 1.f : __expf(v);   // elu+1
          float p = __shfl_xor(v, 1, 64);      // pair partner channel
          float o = fmaf(v, c, sgn * p * s);
          int stride = (EPI == 3) ? 256 : N;
          C[(size_t)row*stride + (col0 + j*16)] = __float2bfloat16(o);
        }
      }
    }
  } else if (EPI == 3) {
    // v half: plain store to C2 at col-256, stride 256
    #pragma unroll
    for (int i = 0; i < 4; i++)
      #pragma unroll
      for (int j = 0; j < 4; j++)
        #pragma unroll
        for (int r = 0; r < 4; r++)
          C2[(size_t)(row0 + i*16 + r)*256 + (col0 - 256 + j*16)] =
              __float2bfloat16(acc[i][j][r]);
  } else {
    #pragma unroll
    for (int i = 0; i < 4; i++)
      #pragma unroll
      for (int j = 0; j < 4; j++)
        #pragma unroll
        for (int r = 0; r < 4; r++) {
          float v = acc[i][j][r];
          if (EPI == 1) v = fmaxf(v, 0.f);
          C[(size_t)(row0 + i*16 + r)*N + (col0 + j*16)] = __float2bfloat16(v);
        }
  }
}

// ---------------- KV partials: no atomics --------------------------------
#define KVPAD 36   // f32 row stride: 144 B = 16B-aligned, breaks bank cycle
__global__ __launch_bounds__(256) void kv_kernel(
    const bf16* __restrict__ Kr, const bf16* __restrict__ V,
    float* __restrict__ KVp, float* __restrict__ Ksp)
{
  __shared__ __align__(16) float Kf[128*KVPAD];  // 18 KB
  __shared__ __align__(16) float Vf[128*KVPAD];  // 18 KB
  const int nh = blockIdx.x;               // n*8+h
  const int n = nh >> 3, h = nh & 7;
  const int cs = blockIdx.y;               // 32 chunks of 512 rows
  const int s0 = cs << 9;
  const int tid = threadIdx.x;
  const int d = tid >> 3, e0 = (tid & 7) << 2;

  float acc0 = 0.f, acc1 = 0.f, acc2 = 0.f, acc3 = 0.f, ks = 0.f;

  for (int sub = 0; sub < 4; sub++) {
    const int sb = s0 + sub*128;
    #pragma unroll
    for (int u = tid; u < 512; u += 256) {
      int row = u >> 2, d0 = (u & 3) << 3;
      size_t gg = (((size_t)(n*LL + sb + row)*NHD + h) << 5) + d0;
      short8 k8 = *(const short8*)(Kr + gg);
      short8 v8 = *(const short8*)(V + gg);
      float* kp = &Kf[row*KVPAD + d0];
      float* vp = &Vf[row*KVPAD + d0];
      float4 ka = {u2f((unsigned short)k8[0]), u2f((unsigned short)k8[1]),
                   u2f((unsigned short)k8[2]), u2f((unsigned short)k8[3])};
      float4 kb = {u2f((unsigned short)k8[4]), u2f((unsigned short)k8[5]),
                   u2f((unsigned short)k8[6]), u2f((unsigned short)k8[7])};
      float4 va = {u2f((unsigned short)v8[0]), u2f((unsigned short)v8[1]),
                   u2f((unsigned short)v8[2]), u2f((unsigned short)v8[3])};
      float4 vb = {u2f((unsigned short)v8[4]), u2f((unsigned short)v8[5]),
                   u2f((unsigned short)v8[6]), u2f((unsigned short)v8[7])};
      *(float4*)kp = ka; *(float4*)(kp+4) = kb;
      *(float4*)vp = va; *(float4*)(vp+4) = vb;
    }
    __syncthreads();
    #pragma unroll 8
    for (int ss = 0; ss < 128; ss++) {
      float kd = Kf[ss*KVPAD + d];                     // broadcast (8 lanes)
      float4 v4 = *(const float4*)&Vf[ss*KVPAD + e0];  // broadcast (8 lanes)
      acc0 = fmaf(kd, v4.x, acc0);
      acc1 = fmaf(kd, v4.y, acc1);
      acc2 = fmaf(kd, v4.z, acc2);
      acc3 = fmaf(kd, v4.w, acc3);
      ks += kd;
    }
    __syncthreads();
  }

  float* kvp = KVp + (((size_t)nh << 5) + cs) * 1024 + (tid << 2);
  kvp[0] = acc0; kvp[1] = acc1; kvp[2] = acc2; kvp[3] = acc3;
  if ((tid & 7) == 0) Ksp[(((size_t)nh << 5) + cs) * 32 + d] = ks;
}

// ---------------- reduce partials -> KV[nh][1024], Ksum[nh][32] ----------
__global__ __launch_bounds__(256) void reduce_kv_kernel(
    const float* __restrict__ KVp, const float* __restrict__ Ksp,
    float* __restrict__ KV, float* __restrict__ Ksum)
{
  const int nh = blockIdx.x;
  const int tid = threadIdx.x;
  float4 acc = {0.f,0.f,0.f,0.f};
  #pragma unroll 8
  for (int cs = 0; cs < 32; cs++) {
    float4 p = *(const float4*)(KVp + (((size_t)nh << 5) + cs) * 1024 + (tid << 2));
    acc.x += p.x; acc.y += p.y; acc.z += p.z; acc.w += p.w;
  }
  *(float4*)(KV + ((size_t)nh << 10) + (tid << 2)) = acc;
  if (tid < 32) {
    float s = 0.f;
    #pragma unroll 8
    for (int cs = 0; cs < 32; cs++)
      s += Ksp[(((size_t)nh << 5) + cs) * 32 + tid];
    Ksum[(nh << 5) + tid] = s;
  }
}

// ---------------- out[l,h,e] = (Q_h . KV_h[:,e]) / (Q_h . Ksum_h + eps) ---
__global__ __launch_bounds__(256) void attn_out_kernel(
    const bf16* __restrict__ Qr, const float* __restrict__ KV,
    const float* __restrict__ Ksum, bf16* __restrict__ Out)
{
  __shared__ float KVs[8192];
  __shared__ float Kss[256];
  __shared__ float Qs[16][256];
  const int blk = blockIdx.x;            // 4096 blocks, 16 rows each
  const int n = blk >> 10;               // 1024 blocks per batch
  const int tid = threadIdx.x;
  const size_t rowBase = (size_t)blk * 16;
  for (int i = tid; i < 8192; i += 256) KVs[i] = KV[((size_t)n << 13) + i];
  Kss[tid] = Ksum[(n << 8) + tid];
  #pragma unroll
  for (int it = 0; it < 2; it++) {
    int i = it*256 + tid;                // 8-elem unit, 512 units total
    short8 u = *(const short8*)(Qr + (rowBase << 8) + (size_t)i*8);
    float* qp = ((float*)Qs) + (size_t)i*8;
    #pragma unroll
    for (int j = 0; j < 8; j++) qp[j] = u2f((unsigned short)u[j]);
  }
  __syncthreads();
  const int h = tid >> 5, e = tid & 31;
  const float* kvh = &KVs[(h << 10) + e];
  const float* ksh = &Kss[h << 5];
  for (int r = 0; r < 16; r++) {
    const float* qh = &Qs[r][h << 5];
    float denom = 1e-6f;
    float num = 0.f;
    #pragma unroll
    for (int d = 0; d < 32; d++) {
      float qd = qh[d];
      denom = fmaf(qd, ksh[d], denom);
      num   = fmaf(qd, kvh[d << 5], num);
    }
    Out[((rowBase + r) << 8) + tid] = __float2bfloat16(num / denom);
  }
}

// ---------------- LayerNorm over 256: 1 wave/row, 4 rows/block -----------
// No LDS, no barriers: in-wave shfl_xor butterfly; 8-16B/lane loads/stores.
__global__ __launch_bounds__(256) void ln_kernel(
    const bf16* __restrict__ X, const float* __restrict__ g, const float* __restrict__ b,
    bf16* __restrict__ Out)
{
  const int tid = threadIdx.x;
  const int wave = tid >> 6, lane = tid & 63;
  const size_t row = (size_t)blockIdx.x*4 + wave;
  const size_t base = (row << 8) + lane*4;
  ushort4 u = *(const ushort4*)(X + base);
  float v0 = u2f(u.x), v1 = u2f(u.y), v2 = u2f(u.z), v3 = u2f(u.w);
  float s  = v0 + v1 + v2 + v3;
  float sq = v0*v0 + v1*v1 + v2*v2 + v3*v3;
  #pragma unroll
  for (int o = 1; o < 64; o <<= 1) {
    s  += __shfl_xor(s,  o, 64);
    sq += __shfl_xor(sq, o, 64);
  }
  float mean = s * (1.f/256.f);
  float var  = sq * (1.f/256.f) - mean*mean;
  float rstd = rsqrtf(var + 1e-5f);
  float4 gv = *(const float4*)(g + lane*4);
  float4 bv = *(const float4*)(b + lane*4);
  unsigned short t[4] = {
    f2u((v0 - mean)*rstd*gv.x + bv.x),
    f2u((v1 - mean)*rstd*gv.y + bv.y),
    f2u((v2 - mean)*rstd*gv.z + bv.z),
    f2u((v3 - mean)*rstd*gv.w + bv.w)};
  *(uint2*)(Out + base) = *(uint2*)t;
}

// ---------------- final: out = x + LN(h2): 1 wave/row, 4 rows/block ------
__global__ __launch_bounds__(256) void ln_add_kernel(
    const bf16* __restrict__ X, const float* __restrict__ g, const float* __restrict__ b,
    const float* __restrict__ xin, float* __restrict__ Out)
{
  const int tid = threadIdx.x;
  const int wave = tid >> 6, lane = tid & 63;
  const size_t row = (size_t)blockIdx.x*4 + wave;
  const size_t base = (row << 8) + lane*4;
  ushort4 u = *(const ushort4*)(X + base);
  float v0 = u2f(u.x), v1 = u2f(u.y), v2 = u2f(u.z), v3 = u2f(u.w);
  float s  = v0 + v1 + v2 + v3;
  float sq = v0*v0 + v1*v1 + v2*v2 + v3*v3;
  #pragma unroll
  for (int o = 1; o < 64; o <<= 1) {
    s  += __shfl_xor(s,  o, 64);
    sq += __shfl_xor(sq, o, 64);
  }
  float mean = s * (1.f/256.f);
  float var  = sq * (1.f/256.f) - mean*mean;
  float rstd = rsqrtf(var + 1e-5f);
  float4 gv = *(const float4*)(g + lane*4);
  float4 bv = *(const float4*)(b + lane*4);
  float4 xv = *(const float4*)(xin + base);
  float4 ov = {
    xv.x + (v0 - mean)*rstd*gv.x + bv.x,
    xv.y + (v1 - mean)*rstd*gv.y + bv.y,
    xv.z + (v2 - mean)*rstd*gv.z + bv.z,
    xv.w + (v3 - mean)*rstd*gv.w + bv.w};
  *(float4*)(Out + base) = ov;
}

extern "C" void kernel_launch(void* const* d_in, const int* in_sizes, int n_in,
                              void* d_out, int out_size, void* d_ws, size_t ws_size,
                              hipStream_t stream) {
  const float* x   = (const float*)d_in[0];
  const float* src = (const float*)d_in[1];
  const float* Wq  = (const float*)d_in[2];
  const float* Wk  = (const float*)d_in[3];
  const float* Wv  = (const float*)d_in[4];
  const float* Wm  = (const float*)d_in[5];
  const float* W1  = (const float*)d_in[6];
  const float* W2  = (const float*)d_in[7];
  const float* g1  = (const float*)d_in[8];
  const float* b1  = (const float*)d_in[9];
  const float* g2  = (const float*)d_in[10];
  const float* b2  = (const float*)d_in[11];
  float* out = (float*)d_out;

  bf16* ws = (bf16*)d_ws;
  const size_t BUFH = (size_t)MROWS * CC;   // 16,777,216 bf16 = 32 MB
  bf16* R0 = ws;               // xb (live until W1 gemm)
  bf16* R1 = ws + BUFH;        // sb -> q -> h1(lo)
  bf16* R2 = ws + 2*BUFH;      // k -> attn -> h1(hi)
  bf16* R3 = ws + 3*BUFH;      // v -> msg -> h2
  bf16* WB = ws + 4*BUFH;      // bf16 weights, 655360 elems (1.25 MB)
  bf16* wq = WB, *wk = WB+65536, *wv = WB+131072, *wm = WB+196608,
      *w1 = WB+262144, *w2 = WB+524288;
  float* KV   = (float*)(WB + 655360);      // 32768 f32
  float* Ksum = KV + NB*NHD*DH*DH;          // 1024 f32
  // KV partials live in d_out (64 MB, overwritten only by final ln_add):
  float* KVp = out;                         // 32*32*1024 f32 = 4 MB
  float* Ksp = out + 32*32*1024;            // 32*32*32 f32 = 128 KB

  dim3 blk(256);
  const int n8 = MROWS*CC/8;
  convert_kernel<<<(n8+255)/256, blk, 0, stream>>>(x,   R0, n8);
  convert_kernel<<<(n8+255)/256, blk, 0, stream>>>(src, R1, n8);
  convert_weights_kernel<<<320, blk, 0, stream>>>(Wq, Wk, Wv, Wm, W1, W2, WB);

  const int G256 = (MROWS/128)*(CC/128);    // 1024 blocks
  const int G512 = (MROWS/128)*(2*CC/128);  // 2048 blocks
  // fused: [k|v] = sb @ [wk;wv]^T -> k(rope)->R2, v->R3 (wk,wv contiguous)
  gemm_m97<3><<<G512, blk, 0, stream>>>(R1, CC, nullptr, wk, R2, R3, MROWS, 2*CC, CC);
  // KV + Ksum via partials (no atomics)
  kv_kernel<<<dim3(NB*NHD, 32), blk, 0, stream>>>(R2, R3, KVp, Ksp);
  reduce_kv_kernel<<<NB*NHD, blk, 0, stream>>>(KVp, Ksp, KV, Ksum);
  // q = rope(elu(xb@Wq^T)+1) -> R1 (sb dead)
  gemm_m97<2><<<G256, blk, 0, stream>>>(R0, CC, nullptr, wq, R1, nullptr, MROWS, CC, CC);
  // attn: q(R1) -> R2 (k dead)
  attn_out_kernel<<<MROWS/16, blk, 0, stream>>>(R1, KV, Ksum, R2);
  // msg = LN1(attn @ Wm^T): attn(R2) -> R3 (v dead)
  gemm_m97<0><<<G256, blk, 0, stream>>>(R2, CC, nullptr, wm, R3, nullptr, MROWS, CC, CC);
  ln_kernel<<<MROWS/4, blk, 0, stream>>>(R3, g1, b1, R3);
  // h1 = relu([xb(R0) | msg(R3)] @ W1^T) -> R1..R2 (64 MB contiguous)
  gemm_m97<1><<<G512, blk, 0, stream>>>(R0, CC, R3, w1, R1, nullptr, MROWS, 2*CC, 2*CC);
  // h2 = h1(R1,K=512) @ W2^T -> R3 (msg dead)
  gemm_m97<0><<<G256, blk, 0, stream>>>(nullptr, 0, R1, w2, R3, nullptr, MROWS, CC, 2*CC);
  // out = x + LN2(h2)
  ln_add_kernel<<<MROWS/4, blk, 0, stream>>>(R3, g2, b2, x, out);
}